// Round 6
// baseline (786.535 us; speedup 1.0000x reference)
//
#include <hip/hip_runtime.h>
#include <hip/hip_bf16.h>

#define DEVINL __device__ __forceinline__

typedef _Float16 f16;
typedef _Float16 f16x2 __attribute__((ext_vector_type(2)));
typedef _Float16 f16x8 __attribute__((ext_vector_type(8)));
typedef float f32x4 __attribute__((ext_vector_type(4)));

#define MFMA16 __builtin_amdgcn_mfma_f32_16x16x32_f16

DEVINL float gelu_f(float x) {
    return 0.5f * x * (1.0f + erff(x * 0.70710678118654752440f));
}

// XOR swizzle: permute 8-f16 column blocks by row&7 (bank-conflict fix, T2 style)
DEVINL int swz(int col, int row) {
    return (((col >> 3) ^ (row & 7)) << 3) | (col & 7);
}

// ---------------- S4D kernel precompute v2 (table-based, f64 tables) -----------
// k[h,l] = 2*Re( sum_n Ck[h,n] * E1^l ), E1 = exp(dtA); E1^l = E32^(l>>5) * E1^(l&31)
__global__ __launch_bounds__(256)
void s4k2_kernel(float* __restrict__ kout,
                 const float* __restrict__ log_dt, const float* __restrict__ Cre,
                 const float* __restrict__ Cim, const float* __restrict__ logAre,
                 const float* __restrict__ Aim, int L)
{
    __shared__ double EaR[64][16], EaI[64][16];
    __shared__ double EbR[64][32], EbI[64][32];
    __shared__ double CkR[64], CkI[64];
    int h = blockIdx.x, tid = threadIdx.x;
    if (tid < 64) {
        int n = tid;
        double dt = exp((double)log_dt[h]);
        double Ar = -exp((double)logAre[h * 64 + n]);
        double Ai = (double)Aim[h * 64 + n];
        double dr = Ar * dt, di = Ai * dt;
        double edr = exp(dr);
        double E1r = edr * cos(di), E1i = edr * sin(di);
        double den = Ar * Ar + Ai * Ai;
        double tr = ((E1r - 1.0) * Ar + E1i * Ai) / den;
        double ti = (E1i * Ar - (E1r - 1.0) * Ai) / den;
        double Cr = (double)Cre[h * 64 + n], Ci = (double)Cim[h * 64 + n];
        CkR[n] = Cr * tr - Ci * ti;
        CkI[n] = Cr * ti + Ci * tr;
        double br = 1.0, bi = 0.0;
        for (int b2 = 0; b2 < 32; ++b2) {
            EbR[n][b2] = br; EbI[n][b2] = bi;
            double nr = br * E1r - bi * E1i;
            bi = br * E1i + bi * E1r; br = nr;
        }
        double E32r = br, E32i = bi;          // E1^32
        double ar2 = 1.0, ai2 = 0.0;
        for (int a = 0; a < 16; ++a) {
            EaR[n][a] = ar2; EaI[n][a] = ai2;
            double nr = ar2 * E32r - ai2 * E32i;
            ai2 = ar2 * E32i + ai2 * E32r; ar2 = nr;
        }
    }
    __syncthreads();
    for (int l = tid; l < L; l += 256) {
        int a = l >> 5, b2 = l & 31;
        double acc = 0.0;
        for (int n = 0; n < 64; ++n) {
            double er = EaR[n][a] * EbR[n][b2] - EaI[n][a] * EbI[n][b2];
            double ei = EaR[n][a] * EbI[n][b2] + EaI[n][a] * EbR[n][b2];
            acc += CkR[n] * er - CkI[n] * ei;
        }
        kout[h * L + l] = (float)(2.0 * acc);
    }
}

// ---------------- weight / emb packing ----------------
__global__ __launch_bounds__(256)
void pack_t_kernel(f16* __restrict__ dst, const float* __restrict__ src,
                   int R, int C)
{
    int idx = blockIdx.x * 256 + threadIdx.x;
    int r = idx / C, c = idx - r * C;
    dst[idx] = (f16)src[c * R + r];
}
__global__ __launch_bounds__(256)
void pack_n_kernel(f16* __restrict__ dst, const float* __restrict__ src, int n)
{
    int idx = blockIdx.x * 256 + threadIdx.x;
    if (idx < n) dst[idx] = (f16)src[idx];
}
// emb (50000 x 256 f32) -> f16, 8 elems/thread, 6250 blocks exact
__global__ __launch_bounds__(256)
void packemb_kernel(f16* __restrict__ dst, const float* __restrict__ src)
{
    long i = ((long)blockIdx.x * 256 + threadIdx.x) * 8;
    float4 a = *(const float4*)(src + i);
    float4 b = *(const float4*)(src + i + 4);
    f16x8 o;
    o[0]=(f16)a.x; o[1]=(f16)a.y; o[2]=(f16)a.z; o[3]=(f16)a.w;
    o[4]=(f16)b.x; o[5]=(f16)b.y; o[6]=(f16)b.z; o[7]=(f16)b.w;
    *(f16x8*)(dst + i) = o;
}

// ---------------- Toeplitz B-fragment precompute --------------------------------
__global__ __launch_bounds__(256)
void toep_kernel(f16* __restrict__ tf, const float* __restrict__ kW)
{
    int idx = blockIdx.x * 256 + threadIdx.x;      // 4194304
    int r = idx & 7;
    int lane = (idx >> 3) & 63;
    int nn = (idx >> 9) & 3;
    int s = (idx >> 11) & 1;
    int d = (idx >> 12) & 7;
    int h = idx >> 15;
    int widx = 64 * d + 16 * nn + (lane & 15) - 32 * s - 8 * (lane >> 4) - r;
    float v = (widx >= 0 && widx < 512) ? kW[h * 512 + widx] : 0.f;
    tf[idx] = (f16)v;
}

// ---------------- enc MFMA: gather emb16 rows, GEMM K=256 N=128 -> (b,h,l) f16 --
__global__ __launch_bounds__(256)
void enc_mfma(const f16* __restrict__ emb16, const int* __restrict__ ids,
              long tok_base, const f16* __restrict__ WT /*[128][256]*/,
              const float* __restrict__ bias, f16* __restrict__ u)
{
    __shared__ f16 As[64][40];
    __shared__ f16 Bs[128][40];
    __shared__ f16 zs[128][72];
    int tid = threadIdx.x;
    int wave = tid >> 6, lane = tid & 63;
    long m0 = (long)blockIdx.x * 64;
    int b_local = (int)(m0 >> 9), l0 = (int)(m0 & 511);

    f32x4 acc[8] = {};

    int am = tid >> 2, aseg = tid & 3;
    int gidx = ids[tok_base + m0 + am];
    const f16* aptr = emb16 + (long)gidx * 256 + aseg * 8;
    int bn = tid >> 1, bseg = tid & 1;
    const f16* bptr = WT + (long)bn * 256 + bseg * 16;

    for (int k0 = 0; k0 < 256; k0 += 32) {
        f16x8 av = *(const f16x8*)(aptr + k0);
        f16x8 b0 = *(const f16x8*)(bptr + k0);
        f16x8 b1 = *(const f16x8*)(bptr + k0 + 8);
        __syncthreads();
        *(f16x8*)&As[am][aseg * 8] = av;
        *(f16x8*)&Bs[bn][bseg * 16] = b0;
        *(f16x8*)&Bs[bn][bseg * 16 + 8] = b1;
        __syncthreads();
        f16x8 af = *(const f16x8*)&As[16 * wave + (lane & 15)][8 * (lane >> 4)];
#pragma unroll
        for (int nn = 0; nn < 8; ++nn) {
            f16x8 bf = *(const f16x8*)&Bs[nn * 16 + (lane & 15)][8 * (lane >> 4)];
            acc[nn] = MFMA16(af, bf, acc[nn], 0, 0, 0);
        }
    }
    __syncthreads();
#pragma unroll
    for (int nn = 0; nn < 8; ++nn) {
        int h = nn * 16 + (lane & 15);
        float bv = bias[h];
#pragma unroll
        for (int reg = 0; reg < 4; ++reg) {
            int l = 16 * wave + 4 * (lane >> 4) + reg;
            zs[h][l] = (f16)(acc[nn][reg] + bv);
        }
    }
    __syncthreads();
    f16* ub = u + (long)b_local * 65536 + l0;
#pragma unroll
    for (int it = 0; it < 4; ++it) {
        int h = (tid >> 3) + 32 * it, seg = tid & 7;
        *(f16x8*)(ub + (long)h * 512 + seg * 8) = *(const f16x8*)&zs[h][seg * 8];
    }
}

// ---------------- conv2: per-(h, 64-sent) block, all 8 l-tiles, stage u once ----
// y[b,h,l] = gelu( sum_j u[b,h,j] k[h,l-j] + u[b,h,l]*D[h] )
__global__ __launch_bounds__(256)
void conv2_mfma(const f16* __restrict__ u, const f16* __restrict__ tf,
                const float* __restrict__ Dv, f16* __restrict__ y, int SC)
{
    __shared__ f16 As[64][72];
    __shared__ f16 ys[64][72];
    int h = blockIdx.x, b0 = blockIdx.y * 64;
    int tid = threadIdx.x, wave = tid >> 6, lane = tid & 63;
    float Dh = Dv[h];
    int ar = tid >> 2, aseg = tid & 3;
    bool arow_ok = (b0 + ar) < SC;
    const f16* ubase = u + ((long)(b0 + ar) * 128 + h) * 512;

    f32x4 acc[8][4] = {};   // [l-tile][nn], all statically indexed (full unroll)

#pragma unroll
    for (int jt = 0; jt < 8; ++jt) {
        f16x8 av0 = {}, av1 = {};
        if (arow_ok) {
            av0 = *(const f16x8*)(ubase + jt * 64 + aseg * 16);
            av1 = *(const f16x8*)(ubase + jt * 64 + aseg * 16 + 8);
        }
        __syncthreads();                       // prior ys reads / As reads done
        *(f16x8*)&As[ar][aseg * 16]     = av0;
        *(f16x8*)&As[ar][aseg * 16 + 8] = av1;
        __syncthreads();
#pragma unroll
        for (int Lt = jt; Lt < 8; ++Lt) {
            const f16* tfb = tf + (((long)h * 8 + (Lt - jt)) * 8) * 512 + lane * 8;
#pragma unroll
            for (int s = 0; s < 2; ++s) {
                f16x8 af = *(const f16x8*)&As[16 * wave + (lane & 15)][32 * s + 8 * (lane >> 4)];
#pragma unroll
                for (int nn = 0; nn < 4; ++nn) {
                    f16x8 bf = *(const f16x8*)(tfb + ((long)s * 4 + nn) * 512);
                    acc[Lt][nn] = MFMA16(af, bf, acc[Lt][nn], 0, 0, 0);
                }
            }
        }
        // tile Lt == jt is now complete; As still holds its diagonal u tile
#pragma unroll
        for (int nn = 0; nn < 4; ++nn) {
#pragma unroll
            for (int reg = 0; reg < 4; ++reg) {
                int bl = 16 * wave + 4 * (lane >> 4) + reg;
                int ll = 16 * nn + (lane & 15);
                ys[bl][ll] = (f16)gelu_f(acc[jt][nn][reg] + (float)As[bl][ll] * Dh);
            }
        }
        __syncthreads();
#pragma unroll
        for (int it = 0; it < 2; ++it) {
            int unit = tid + 256 * it;
            int r = unit >> 3, seg = unit & 7;
            if (b0 + r < SC)
                *(f16x8*)(y + ((long)(b0 + r) * 128 + h) * 512 + jt * 64 + seg * 8)
                    = *(const f16x8*)&ys[r][seg * 8];
        }
    }
}

// ---------------- fused GLU + residual + LN + d1 + mean-pool --------------------
// per (b, l-tile 64): z[l,o]=(convW[o,:]@y+cb[o])*sig(convW[o+128,:]@y+cb[o+128])+u[o,l]
// LN over o -> xt (in LDS) -> h = gelu(xt@d1W+b1) -> pool atomics into hbar.
#define PITCH 144
__global__ __launch_bounds__(256)
void gld_mfma(const f16* __restrict__ y, const f16* __restrict__ u,
              const f16* __restrict__ WT /*convWT [256][128]*/,
              const float* __restrict__ cb, const float* __restrict__ lng,
              const float* __restrict__ lnb,
              const f16* __restrict__ W1T /*d1WT [256][128]*/,
              const float* __restrict__ b1, float* __restrict__ hbar,
              long sent_base)
{
    __shared__ f16 At[64][PITCH];
    __shared__ f16 Ut[64][PITCH];
    __shared__ f16 Bs[256][40];
    __shared__ float red[4][16][16];
    int b = blockIdx.x, l0 = blockIdx.y * 64;
    int tid = threadIdx.x, wave = tid >> 6, lane = tid & 63;

    // ---- stage y^T and u^T, swizzled, h-paired f16x2 writes (conflict-free) ----
#pragma unroll
    for (int it = 0; it < 2; ++it) {
        int unit = tid + 256 * it;       // 0..511
        int hp = unit & 63, seg = unit >> 6;
        int h = hp * 2;
        const f16* yp = y + ((long)b * 128 + h) * 512 + l0 + seg * 8;
        const f16* up = u + ((long)b * 128 + h) * 512 + l0 + seg * 8;
        f16x8 ya = *(const f16x8*)yp;
        f16x8 yb = *(const f16x8*)(yp + 512);
        f16x8 ua = *(const f16x8*)up;
        f16x8 ub = *(const f16x8*)(up + 512);
#pragma unroll
        for (int q = 0; q < 8; ++q) {
            int l = seg * 8 + q;
            int ix = swz(h, l);
            f16x2 py; py[0] = ya[q]; py[1] = yb[q];
            f16x2 pu; pu[0] = ua[q]; pu[1] = ub[q];
            *(f16x2*)&At[l][ix] = py;
            *(f16x2*)&Ut[l][ix] = pu;
        }
    }

    // ---- GLU GEMM ----
    f32x4 acc[16] = {};
    for (int k0 = 0; k0 < 128; k0 += 32) {
        f16x8 breg[4];
#pragma unroll
        for (int it = 0; it < 4; ++it) {
            int unit = tid + 256 * it;
            int n = unit >> 2, seg = unit & 3;
            breg[it] = *(const f16x8*)(WT + (long)n * 128 + k0 + seg * 8);
        }
        __syncthreads();
#pragma unroll
        for (int it = 0; it < 4; ++it) {
            int unit = tid + 256 * it;
            int n = unit >> 2, seg = unit & 3;
            *(f16x8*)&Bs[n][seg * 8] = breg[it];
        }
        __syncthreads();
        int arow = 16 * wave + (lane & 15);
        f16x8 af = *(const f16x8*)&At[arow][swz(k0 + 8 * (lane >> 4), arow)];
#pragma unroll
        for (int nn = 0; nn < 16; ++nn) {
            f16x8 bf = *(const f16x8*)&Bs[nn * 16 + (lane & 15)][8 * (lane >> 4)];
            acc[nn] = MFMA16(af, bf, acc[nn], 0, 0, 0);
        }
    }

    // ---- GLU + residual + LN stats ----
    float zz[8][4];
    float sum[4] = {0.f,0.f,0.f,0.f}, sq[4] = {0.f,0.f,0.f,0.f};
#pragma unroll
    for (int nn = 0; nn < 8; ++nn) {
        int o = nn * 16 + (lane & 15);
        float ca = cb[o], cbb = cb[o + 128];
#pragma unroll
        for (int reg = 0; reg < 4; ++reg) {
            int l = 16 * wave + 4 * (lane >> 4) + reg;
            float a = acc[nn][reg] + ca;
            float bbv = acc[nn + 8][reg] + cbb;
            float z = a * (1.0f / (1.0f + expf(-bbv))) + (float)Ut[l][swz(o, l)];
            zz[nn][reg] = z;
            sum[reg] += z; sq[reg] += z * z;
        }
    }
#pragma unroll
    for (int d = 1; d < 16; d <<= 1) {
#pragma unroll
        for (int reg = 0; reg < 4; ++reg) {
            sum[reg] += __shfl_xor(sum[reg], d);
            sq[reg]  += __shfl_xor(sq[reg], d);
        }
    }
    float mu[4], rs[4];
#pragma unroll
    for (int reg = 0; reg < 4; ++reg) {
        mu[reg] = sum[reg] * (1.0f / 128.0f);
        float var = sq[reg] * (1.0f / 128.0f) - mu[reg] * mu[reg];
        rs[reg] = rsqrtf(var + 1e-5f);
    }
    __syncthreads();          // all glu-phase At frag reads complete
    // write xt into At (swizzled)
#pragma unroll
    for (int nn = 0; nn < 8; ++nn) {
        int o = nn * 16 + (lane & 15);
        float g = lng[o], bta = lnb[o];
#pragma unroll
        for (int reg = 0; reg < 4; ++reg) {
            int l = 16 * wave + 4 * (lane >> 4) + reg;
            At[l][swz(o, l)] = (f16)((zz[nn][reg] - mu[reg]) * rs[reg] * g + bta);
        }
    }

    // ---- d1 GEMM (A = xt tile in LDS) ----
    f32x4 acc2[16] = {};
    for (int k0 = 0; k0 < 128; k0 += 32) {
        f16x8 breg[4];
#pragma unroll
        for (int it = 0; it < 4; ++it) {
            int unit = tid + 256 * it;
            int n = unit >> 2, seg = unit & 3;
            breg[it] = *(const f16x8*)(W1T + (long)n * 128 + k0 + seg * 8);
        }
        __syncthreads();      // also orders xt writes before af2 reads (1st iter)
#pragma unroll
        for (int it = 0; it < 4; ++it) {
            int unit = tid + 256 * it;
            int n = unit >> 2, seg = unit & 3;
            *(f16x8*)&Bs[n][seg * 8] = breg[it];
        }
        __syncthreads();
        int arow = 16 * wave + (lane & 15);
        f16x8 af = *(const f16x8*)&At[arow][swz(k0 + 8 * (lane >> 4), arow)];
#pragma unroll
        for (int nn = 0; nn < 16; ++nn) {
            f16x8 bf = *(const f16x8*)&Bs[nn * 16 + (lane & 15)][8 * (lane >> 4)];
            acc2[nn] = MFMA16(af, bf, acc2[nn], 0, 0, 0);
        }
    }

    // ---- gelu + mean-pool ----
    long sent = sent_base + b;
#pragma unroll
    for (int nn = 0; nn < 16; ++nn) {
        float bv = b1[nn * 16 + (lane & 15)];
        float s = 0.f;
#pragma unroll
        for (int reg = 0; reg < 4; ++reg)
            s += gelu_f(acc2[nn][reg] + bv);
        s += __shfl_xor(s, 16);
        s += __shfl_xor(s, 32);
        if (lane < 16) red[wave][lane][nn] = s;
    }
    __syncthreads();
    if (wave == 0 && lane < 16) {
#pragma unroll
        for (int nn = 0; nn < 16; ++nn) {
            float tot = red[0][lane][nn] + red[1][lane][nn]
                      + red[2][lane][nn] + red[3][lane][nn];
            atomicAdd(&hbar[sent * 256 + nn * 16 + lane], tot * (1.0f / 512.0f));
        }
    }
}

// ======================= f32 kernels (sentence level + d2) ======================
__global__ __launch_bounds__(256)
void gemm_kernel(const float* __restrict__ A, const int* __restrict__ gather,
                 const float* __restrict__ W, const float* __restrict__ bias,
                 float* __restrict__ C, float* __restrict__ pool,
                 long m_base, int K, int N, int act, int poolLen)
{
    __shared__ float As[32][68];
    __shared__ float Ws[32][128];
    __shared__ float red[16][128];

    int tid = threadIdx.x;
    int tx = tid & 15, ty = tid >> 4;
    long m0 = (long)blockIdx.x * 64;
    int n0 = blockIdx.y * 128;

    int la_row = tid >> 2, la_k = (tid & 3) * 8;
    long arow = gather ? (long)gather[m_base + m0 + la_row] : (m0 + la_row);
    const float* Arow = A + arow * (long)K + la_k;
    int wk = tid >> 3, wn = (tid & 7) * 16;
    const float* Wp = W + (long)wk * N + n0 + wn;

    float acc[4][8];
#pragma unroll
    for (int i = 0; i < 4; ++i)
#pragma unroll
        for (int j = 0; j < 8; ++j) acc[i][j] = 0.f;

    for (int k0 = 0; k0 < K; k0 += 32) {
        float4 a0 = *(const float4*)(Arow + k0);
        float4 a1 = *(const float4*)(Arow + k0 + 4);
        const float* wp = Wp + (long)k0 * N;
        float4 w0 = *(const float4*)(wp);
        float4 w1 = *(const float4*)(wp + 4);
        float4 w2 = *(const float4*)(wp + 8);
        float4 w3 = *(const float4*)(wp + 12);
        __syncthreads();
        As[la_k + 0][la_row] = a0.x; As[la_k + 1][la_row] = a0.y;
        As[la_k + 2][la_row] = a0.z; As[la_k + 3][la_row] = a0.w;
        As[la_k + 4][la_row] = a1.x; As[la_k + 5][la_row] = a1.y;
        As[la_k + 6][la_row] = a1.z; As[la_k + 7][la_row] = a1.w;
        *(float4*)&Ws[wk][wn]      = w0;
        *(float4*)&Ws[wk][wn + 4]  = w1;
        *(float4*)&Ws[wk][wn + 8]  = w2;
        *(float4*)&Ws[wk][wn + 12] = w3;
        __syncthreads();
#pragma unroll
        for (int kk = 0; kk < 32; ++kk) {
            float4 av  = *(const float4*)&As[kk][ty * 4];
            float4 wv0 = *(const float4*)&Ws[kk][tx * 4];
            float4 wv1 = *(const float4*)&Ws[kk][64 + tx * 4];
            float a_[4] = {av.x, av.y, av.z, av.w};
            float w_[8] = {wv0.x, wv0.y, wv0.z, wv0.w, wv1.x, wv1.y, wv1.z, wv1.w};
#pragma unroll
            for (int i = 0; i < 4; ++i)
#pragma unroll
                for (int j = 0; j < 8; ++j)
                    acc[i][j] = fmaf(a_[i], w_[j], acc[i][j]);
        }
    }

    float bv[8];
#pragma unroll
    for (int j = 0; j < 8; ++j) {
        int col = (j < 4) ? (tx * 4 + j) : (64 + tx * 4 + (j - 4));
        bv[j] = bias[n0 + col];
    }
#pragma unroll
    for (int i = 0; i < 4; ++i)
#pragma unroll
        for (int j = 0; j < 8; ++j) {
            float v = acc[i][j] + bv[j];
            if (act == 1) v = gelu_f(v);
            acc[i][j] = v;
        }

    if (pool) {
        float pv[8];
#pragma unroll
        for (int j = 0; j < 8; ++j)
            pv[j] = acc[0][j] + acc[1][j] + acc[2][j] + acc[3][j];
        __syncthreads();
#pragma unroll
        for (int j = 0; j < 8; ++j) {
            int col = (j < 4) ? (tx * 4 + j) : (64 + tx * 4 + (j - 4));
            red[ty][col] = pv[j];
        }
        __syncthreads();
        if (ty == 0) {
            long sent = (m_base + m0) / poolLen;
            float inv = 1.0f / (float)poolLen;
#pragma unroll
            for (int j = 0; j < 8; ++j) {
                int col = (j < 4) ? (tx * 4 + j) : (64 + tx * 4 + (j - 4));
                float s = 0.f;
#pragma unroll
                for (int t = 0; t < 16; ++t) s += red[t][col];
                atomicAdd(&pool[sent * N + n0 + col], s * inv);
            }
        }
    } else if (C) {
#pragma unroll
        for (int i = 0; i < 4; ++i) {
            long m = m0 + ty * 4 + i;
            float* cp = C + m * (long)N + n0;
            float4 s0 = {acc[i][0], acc[i][1], acc[i][2], acc[i][3]};
            float4 s1 = {acc[i][4], acc[i][5], acc[i][6], acc[i][7]};
            *(float4*)(cp + tx * 4) = s0;
            *(float4*)(cp + 64 + tx * 4) = s1;
        }
    }
}

__global__ __launch_bounds__(256)
void transpose_kernel(const float* __restrict__ in, float* __restrict__ out,
                      int L, int H)
{
    __shared__ float t[32][33];
    int b = blockIdx.x, l0 = blockIdx.y * 32, h0 = blockIdx.z * 32;
    int tid = threadIdx.x;
    int c = tid & 31, r = tid >> 5;
    const float* ib = in + ((long)b * L + l0) * H + h0;
#pragma unroll
    for (int i = 0; i < 4; ++i)
        t[r + 8 * i][c] = ib[(long)(r + 8 * i) * H + c];
    __syncthreads();
    float* ob = out + ((long)b * H + h0) * L + l0;
#pragma unroll
    for (int i = 0; i < 4; ++i)
        ob[(long)(r + 8 * i) * L + c] = t[c][r + 8 * i];
}

__global__ __launch_bounds__(256)
void conv_kernel(const float* __restrict__ u, const float* __restrict__ kmat,
                 float* __restrict__ y, int NB, int L)
{
    __shared__ float Ut[64][68];
    __shared__ float kwin[128];
    int h = blockIdx.x;
    int b0 = blockIdx.y * 64, l0 = blockIdx.z * 64;
    int tid = threadIdx.x, tx = tid & 15, ty = tid >> 4;
    const float* kh = kmat + (long)h * L;

    float acc[4][4];
#pragma unroll
    for (int i = 0; i < 4; ++i)
#pragma unroll
        for (int j = 0; j < 4; ++j) acc[i][j] = 0.f;

    int ur = tid >> 2, uc = (tid & 3) * 16;

    for (int j0 = 0; j0 <= l0 + 63; j0 += 64) {
        float4 u0 = {0,0,0,0}, u1 = {0,0,0,0}, u2 = {0,0,0,0}, u3 = {0,0,0,0};
        if (b0 + ur < NB) {
            const float* up = u + ((long)(b0 + ur) * 128 + h) * L + j0 + uc;
            u0 = *(const float4*)up;        u1 = *(const float4*)(up + 4);
            u2 = *(const float4*)(up + 8);  u3 = *(const float4*)(up + 12);
        }
        float kv_ = 0.f;
        int d = l0 - j0 - 63 + tid;
        if (tid < 128) kv_ = (d >= 0 && d < L) ? kh[d] : 0.f;
        __syncthreads();
        {
            float uv[16] = {u0.x,u0.y,u0.z,u0.w, u1.x,u1.y,u1.z,u1.w,
                            u2.x,u2.y,u2.z,u2.w, u3.x,u3.y,u3.z,u3.w};
#pragma unroll
            for (int q = 0; q < 16; ++q) Ut[uc + q][ur] = uv[q];
        }
        if (tid < 128) kwin[tid] = kv_;
        __syncthreads();
#pragma unroll
        for (int jj = 0; jj < 64; ++jj) {
            float4 uv = *(const float4*)&Ut[jj][ty * 4];
            float ub[4] = {uv.x, uv.y, uv.z, uv.w};
            float kj[4];
#pragma unroll
            for (int j = 0; j < 4; ++j) kj[j] = kwin[63 + tx * 4 + j - jj];
#pragma unroll
            for (int i = 0; i < 4; ++i)
#pragma unroll
                for (int j = 0; j < 4; ++j)
                    acc[i][j] = fmaf(ub[i], kj[j], acc[i][j]);
        }
    }
#pragma unroll
    for (int i = 0; i < 4; ++i) {
        int b = b0 + ty * 4 + i;
        if (b < NB) {
            float4 s = {acc[i][0], acc[i][1], acc[i][2], acc[i][3]};
            *(float4*)(y + ((long)b * 128 + h) * L + l0 + tx * 4) = s;
        }
    }
}

__global__ __launch_bounds__(256)
void skipgelu_kernel(float* __restrict__ y, const float* __restrict__ u,
                     const float* __restrict__ D, int log2L, long total)
{
    long i = (long)blockIdx.x * 256 + threadIdx.x;
    long stride = (long)gridDim.x * 256;
    for (; i < total; i += stride) {
        int h = (int)((i >> log2L) & 127);
        float v = y[i] + u[i] * D[h];
        y[i] = gelu_f(v);
    }
}

__global__ __launch_bounds__(256)
void glu_kernel(const float* __restrict__ convW, const float* __restrict__ convb,
                const float* __restrict__ g, const float* u,
                float* z, int L)
{
    __shared__ float Wa[32][68], Wb[32][68], Gs[32][72];
    int b = blockIdx.x, o0 = blockIdx.y * 64, l0 = blockIdx.z * 64;
    int tid = threadIdx.x, tx = tid & 15, ty = tid >> 4;
    const float* gb = g + (long)b * 128 * L;

    float aa[4][4], ab[4][4];
#pragma unroll
    for (int i = 0; i < 4; ++i)
#pragma unroll
        for (int j = 0; j < 4; ++j) { aa[i][j] = 0.f; ab[i][j] = 0.f; }

    int wr = tid >> 2, wc = (tid & 3) * 8;
    int gh = tid >> 3, gl = (tid & 7) * 8;

    for (int k0 = 0; k0 < 128; k0 += 32) {
        float4 wa0 = *(const float4*)(convW + (long)(o0 + wr) * 128 + k0 + wc);
        float4 wa1 = *(const float4*)(convW + (long)(o0 + wr) * 128 + k0 + wc + 4);
        float4 wb0 = *(const float4*)(convW + (long)(o0 + wr + 128) * 128 + k0 + wc);
        float4 wb1 = *(const float4*)(convW + (long)(o0 + wr + 128) * 128 + k0 + wc + 4);
        float4 g0 = *(const float4*)(gb + (long)(k0 + gh) * L + l0 + gl);
        float4 g1 = *(const float4*)(gb + (long)(k0 + gh) * L + l0 + gl + 4);
        __syncthreads();
        {
            float wav[8] = {wa0.x,wa0.y,wa0.z,wa0.w, wa1.x,wa1.y,wa1.z,wa1.w};
            float wbv[8] = {wb0.x,wb0.y,wb0.z,wb0.w, wb1.x,wb1.y,wb1.z,wb1.w};
#pragma unroll
            for (int q = 0; q < 8; ++q) { Wa[wc + q][wr] = wav[q]; Wb[wc + q][wr] = wbv[q]; }
        }
        *(float4*)&Gs[gh][gl]     = g0;
        *(float4*)&Gs[gh][gl + 4] = g1;
        __syncthreads();
#pragma unroll
        for (int kk = 0; kk < 32; ++kk) {
            float4 wav = *(const float4*)&Wa[kk][ty * 4];
            float4 wbv = *(const float4*)&Wb[kk][ty * 4];
            float4 gv  = *(const float4*)&Gs[kk][tx * 4];
            float wa_[4] = {wav.x, wav.y, wav.z, wav.w};
            float wb_[4] = {wbv.x, wbv.y, wbv.z, wbv.w};
            float g_[4]  = {gv.x, gv.y, gv.z, gv.w};
#pragma unroll
            for (int i = 0; i < 4; ++i)
#pragma unroll
                for (int j = 0; j < 4; ++j) {
                    aa[i][j] = fmaf(wa_[i], g_[j], aa[i][j]);
                    ab[i][j] = fmaf(wb_[i], g_[j], ab[i][j]);
                }
        }
    }
#pragma unroll
    for (int i = 0; i < 4; ++i) {
        int o = o0 + ty * 4 + i;
        float ca = convb[o], cb2 = convb[o + 128];
        const float* up = u + ((long)b * 128 + o) * L + l0 + tx * 4;
        float4 uv = *(const float4*)up;
        float uu[4] = {uv.x, uv.y, uv.z, uv.w};
        float tmp[4];
#pragma unroll
        for (int j = 0; j < 4; ++j) {
            float av = aa[i][j] + ca;
            float bv2 = ab[i][j] + cb2;
            tmp[j] = av * (1.0f / (1.0f + expf(-bv2))) + uu[j];
        }
        float4 outv = {tmp[0], tmp[1], tmp[2], tmp[3]};
        *(float4*)(z + ((long)b * 128 + o) * L + l0 + tx * 4) = outv;
    }
}

__global__ __launch_bounds__(256)
void ln_kernel(const float* __restrict__ z, const float* __restrict__ gamma,
               const float* __restrict__ beta, float* __restrict__ out, int L)
{
    __shared__ float zs[128][65];
    __shared__ float mu_s[64], rs_s[64];
    int b = blockIdx.x, l0 = blockIdx.y * 64;
    const float* zb = z + (long)b * 128 * L;
    int tid = threadIdx.x;
    for (int idx = tid; idx < 128 * 64; idx += 256) {
        int h = idx >> 6, li = idx & 63;
        zs[h][li] = zb[(long)h * L + l0 + li];
    }
    __syncthreads();
    int l = tid >> 2, sub = tid & 3;
    float s = 0.f, sq = 0.f;
    for (int ii = 0; ii < 32; ++ii) {
        int i = (ii + sub * 8) & 31;
        float v = zs[sub * 32 + i][l];
        s += v; sq += v * v;
    }
    s += __shfl_xor(s, 1); sq += __shfl_xor(sq, 1);
    s += __shfl_xor(s, 2); sq += __shfl_xor(sq, 2);
    if (sub == 0) {
        float mu = s * (1.0f / 128.0f);
        float var = sq * (1.0f / 128.0f) - mu * mu;
        mu_s[l] = mu;
        rs_s[l] = rsqrtf(var + 1e-5f);
    }
    __syncthreads();
    for (int idx = tid; idx < 64 * 128; idx += 256) {
        int li = idx >> 7, h = idx & 127;
        float v = (zs[h][li] - mu_s[li]) * rs_s[li];
        out[((long)b * L + l0 + li) * 128 + h] = v * gamma[h] + beta[h];
    }
}

// =============================== host ========================================
extern "C" void kernel_launch(void* const* d_in, const int* in_sizes, int n_in,
                              void* d_out, int out_size, void* d_ws, size_t ws_size,
                              hipStream_t stream)
{
    const int* ids = (const int*)d_in[0];
    const float* emb = (const float*)d_in[1];
    const float* const* wp = (const float* const*)(d_in + 2);
    const float* const* sp = (const float* const*)(d_in + 18);
    enum {ENCW = 0, ENCB, LOGDT, CRE, CIM, LOGARE, AIM, DD,
          CONVW, CONVB, LNG, LNB, D1W, D1B, D2W, D2B};

    char* p = (char*)d_ws;
    auto alloc = [&](size_t bytes) {
        char* r = p; p += (bytes + 255) & ~(size_t)255; return r;
    };
    float* kW    = (float*)alloc(128 * 512 * 4);
    float* kS    = (float*)alloc(128 * 64 * 4);
    float* sents = (float*)alloc(512 * 256 * 4);
    float* hbar  = (float*)alloc(512 * 256 * 4);
    float* su    = (float*)alloc(512 * 128 * 4);
    float* subhl = (float*)alloc(512 * 128 * 4);
    float* sy    = (float*)alloc(512 * 128 * 4);
    float* szb   = (float*)alloc(512 * 128 * 4);
    float* sxt   = (float*)alloc(512 * 128 * 4);
    float* sh    = (float*)alloc(512 * 256 * 4);
    f16* encWT   = (f16*)alloc(128 * 256 * 2);
    f16* convWT  = (f16*)alloc(256 * 128 * 2);
    f16* d1WT    = (f16*)alloc(256 * 128 * 2);
    f16* tf      = (f16*)alloc(4194304L * 2);
    f16* emb16   = (f16*)alloc(12800000L * 2);

    long avail = (long)ws_size - (long)(p - (char*)d_ws);
    int SC = 512;
    while (SC > 1 && 2L * SC * 131072 + 1024 > avail) SC >>= 1;
    int nch = 512 / SC;
    f16* u_c = (f16*)alloc((size_t)SC * 65536 * 2);
    f16* y_c = (f16*)alloc((size_t)SC * 65536 * 2);

    // ---- precompute ----
    hipMemsetAsync(hbar, 0, 512 * 256 * 4, stream);
    packemb_kernel<<<6250, 256, 0, stream>>>(emb16, emb);
    s4k2_kernel<<<128, 256, 0, stream>>>(
        kW, wp[LOGDT], wp[CRE], wp[CIM], wp[LOGARE], wp[AIM], 512);
    s4k2_kernel<<<128, 256, 0, stream>>>(
        kS, sp[LOGDT], sp[CRE], sp[CIM], sp[LOGARE], sp[AIM], 64);
    pack_t_kernel<<<128, 256, 0, stream>>>(encWT, wp[ENCW], 128, 256);
    pack_n_kernel<<<128, 256, 0, stream>>>(convWT, wp[CONVW], 32768);
    pack_t_kernel<<<128, 256, 0, stream>>>(d1WT, wp[D1W], 256, 128);
    toep_kernel<<<16384, 256, 0, stream>>>(tf, kW);

    // ================= word level (f16 MFMA) =================
    for (int c = 0; c < nch; ++c) {
        long tok_base = (long)c * SC * 512;
        enc_mfma<<<SC * 8, 256, 0, stream>>>(
            emb16, ids, tok_base, encWT, wp[ENCB], u_c);
        conv2_mfma<<<dim3(128, (SC + 63) / 64), 256, 0, stream>>>(
            u_c, tf, wp[DD], y_c, SC);
        gld_mfma<<<dim3(SC, 8), 256, 0, stream>>>(
            y_c, u_c, convWT, wp[CONVB], wp[LNG], wp[LNB],
            d1WT, wp[D1B], hbar, (long)c * SC);
    }
    // d2 on pooled h (pool-before-d2 exact: d2 linear)
    gemm_kernel<<<dim3(8, 2), 256, 0, stream>>>(
        hbar, nullptr, wp[D2W], wp[D2B], sents, nullptr, 0, 256, 256, 0, 0);

    // ================= sentence level (f32) =================
    gemm_kernel<<<dim3(8, 1), 256, 0, stream>>>(
        sents, nullptr, sp[ENCW], sp[ENCB], su, nullptr, 0, 256, 128, 0, 0);
    transpose_kernel<<<dim3(8, 2, 4), 256, 0, stream>>>(su, subhl, 64, 128);
    conv_kernel<<<dim3(128, 1, 1), 256, 0, stream>>>(subhl, kS, sy, 8, 64);
    skipgelu_kernel<<<256, 256, 0, stream>>>(sy, subhl, sp[DD], 6, 8L * 128 * 64);
    glu_kernel<<<dim3(8, 2, 1), 256, 0, stream>>>(
        sp[CONVW], sp[CONVB], sy, subhl, szb, 64);
    ln_kernel<<<dim3(8, 1), 256, 0, stream>>>(szb, sp[LNG], sp[LNB], sxt, 64);
    gemm_kernel<<<dim3(8, 2), 256, 0, stream>>>(
        sxt, nullptr, sp[D1W], sp[D1B], sh, nullptr, 0, 128, 256, 1, 0);
    gemm_kernel<<<dim3(8, 2), 256, 0, stream>>>(
        sh, nullptr, sp[D2W], sp[D2B], (float*)d_out, nullptr, 0, 256, 256, 0, 0);
}

// Round 7
// 615.246 us; speedup vs baseline: 1.2784x; 1.2784x over previous
//
#include <hip/hip_runtime.h>
#include <hip/hip_bf16.h>

#define DEVINL __device__ __forceinline__

typedef _Float16 f16;
typedef _Float16 f16x2 __attribute__((ext_vector_type(2)));
typedef _Float16 f16x8 __attribute__((ext_vector_type(8)));
typedef float f32x4 __attribute__((ext_vector_type(4)));

#define MFMA16 __builtin_amdgcn_mfma_f32_16x16x32_f16

DEVINL float gelu_f(float x) {
    return 0.5f * x * (1.0f + erff(x * 0.70710678118654752440f));
}

// XOR swizzle: permute 8-f16 column blocks by row&7 (bank-conflict fix, T2 style)
DEVINL int swz(int col, int row) {
    return (((col >> 3) ^ (row & 7)) << 3) | (col & 7);
}

// ---------------- S4D kernel precompute v2 (table-based, f64 tables) -----------
__global__ __launch_bounds__(256)
void s4k2_kernel(float* __restrict__ kout,
                 const float* __restrict__ log_dt, const float* __restrict__ Cre,
                 const float* __restrict__ Cim, const float* __restrict__ logAre,
                 const float* __restrict__ Aim, int L)
{
    __shared__ double EaR[64][16], EaI[64][16];
    __shared__ double EbR[64][32], EbI[64][32];
    __shared__ double CkR[64], CkI[64];
    int h = blockIdx.x, tid = threadIdx.x;
    if (tid < 64) {
        int n = tid;
        double dt = exp((double)log_dt[h]);
        double Ar = -exp((double)logAre[h * 64 + n]);
        double Ai = (double)Aim[h * 64 + n];
        double dr = Ar * dt, di = Ai * dt;
        double edr = exp(dr);
        double E1r = edr * cos(di), E1i = edr * sin(di);
        double den = Ar * Ar + Ai * Ai;
        double tr = ((E1r - 1.0) * Ar + E1i * Ai) / den;
        double ti = (E1i * Ar - (E1r - 1.0) * Ai) / den;
        double Cr = (double)Cre[h * 64 + n], Ci = (double)Cim[h * 64 + n];
        CkR[n] = Cr * tr - Ci * ti;
        CkI[n] = Cr * ti + Ci * tr;
        double br = 1.0, bi = 0.0;
        for (int b2 = 0; b2 < 32; ++b2) {
            EbR[n][b2] = br; EbI[n][b2] = bi;
            double nr = br * E1r - bi * E1i;
            bi = br * E1i + bi * E1r; br = nr;
        }
        double E32r = br, E32i = bi;
        double ar2 = 1.0, ai2 = 0.0;
        for (int a = 0; a < 16; ++a) {
            EaR[n][a] = ar2; EaI[n][a] = ai2;
            double nr = ar2 * E32r - ai2 * E32i;
            ai2 = ar2 * E32i + ai2 * E32r; ar2 = nr;
        }
    }
    __syncthreads();
    for (int l = tid; l < L; l += 256) {
        int a = l >> 5, b2 = l & 31;
        double acc = 0.0;
        for (int n = 0; n < 64; ++n) {
            double er = EaR[n][a] * EbR[n][b2] - EaI[n][a] * EbI[n][b2];
            double ei = EaR[n][a] * EbI[n][b2] + EaI[n][a] * EbR[n][b2];
            acc += CkR[n] * er - CkI[n] * ei;
        }
        kout[h * L + l] = (float)(2.0 * acc);
    }
}

// ---------------- packing ----------------
// emb (50000 x 256 f32) -> f16
__global__ __launch_bounds__(256)
void packemb_kernel(f16* __restrict__ dst, const float* __restrict__ src)
{
    long i = ((long)blockIdx.x * 256 + threadIdx.x) * 8;
    float4 a = *(const float4*)(src + i);
    float4 b = *(const float4*)(src + i + 4);
    f16x8 o;
    o[0]=(f16)a.x; o[1]=(f16)a.y; o[2]=(f16)a.z; o[3]=(f16)a.w;
    o[4]=(f16)b.x; o[5]=(f16)b.y; o[6]=(f16)b.z; o[7]=(f16)b.w;
    *(f16x8*)(dst + i) = o;
}

// pack B into MFMA fragment order: frag[kk][nn][lane][e] = src[k*sk + o*so]
//   o = nn*16 + (lane&15), k = kk*32 + 8*(lane>>4) + e
__global__ __launch_bounds__(256)
void packfrag_kernel(f16* __restrict__ dst, const float* __restrict__ src,
                     int NN, int sk, int so)
{
    int idx = blockIdx.x * 256 + threadIdx.x;
    int e = idx & 7, lane = (idx >> 3) & 63;
    int rem = idx >> 9;
    int nn = rem % NN, kk = rem / NN;
    int o = nn * 16 + (lane & 15);
    int k = kk * 32 + 8 * (lane >> 4) + e;
    dst[idx] = (f16)src[k * sk + o * so];
}

// ---------------- Toeplitz B-fragment precompute --------------------------------
__global__ __launch_bounds__(256)
void toep_kernel(f16* __restrict__ tf, const float* __restrict__ kW)
{
    int idx = blockIdx.x * 256 + threadIdx.x;      // 4194304
    int r = idx & 7;
    int lane = (idx >> 3) & 63;
    int nn = (idx >> 9) & 3;
    int s = (idx >> 11) & 1;
    int d = (idx >> 12) & 7;
    int h = idx >> 15;
    int widx = 64 * d + 16 * nn + (lane & 15) - 32 * s - 8 * (lane >> 4) - r;
    float v = (widx >= 0 && widx < 512) ? kW[h * 512 + widx] : 0.f;
    tf[idx] = (f16)v;
}

// ---------------- enc v3: direct-global A (gather) + global B frags, 0 k-barriers
__global__ __launch_bounds__(256)
void enc_mfma(const f16* __restrict__ emb16, const int* __restrict__ ids,
              long tok_base, const f16* __restrict__ Wfrag,
              const float* __restrict__ bias, f16* __restrict__ u)
{
    __shared__ f16 zs[128][72];
    int tid = threadIdx.x, wave = tid >> 6, lane = tid & 63;
    long m0 = (long)blockIdx.x * 64;
    int b_local = (int)(m0 >> 9), l0 = (int)(m0 & 511);

    int gidx = ids[tok_base + m0 + 16 * wave + (lane & 15)];
    const f16* arow = emb16 + (long)gidx * 256 + 8 * (lane >> 4);
    const f16* bfp = Wfrag + lane * 8;

    f32x4 acc[8] = {};
#pragma unroll
    for (int kk = 0; kk < 8; ++kk) {
        f16x8 af = *(const f16x8*)(arow + kk * 32);
#pragma unroll
        for (int nn = 0; nn < 8; ++nn) {
            f16x8 bf = *(const f16x8*)(bfp + (kk * 8 + nn) * 512);
            acc[nn] = MFMA16(af, bf, acc[nn], 0, 0, 0);
        }
    }
#pragma unroll
    for (int nn = 0; nn < 8; ++nn) {
        int h = nn * 16 + (lane & 15);
        float bv = bias[h];
#pragma unroll
        for (int reg = 0; reg < 4; ++reg) {
            int l = 16 * wave + 4 * (lane >> 4) + reg;
            zs[h][l] = (f16)(acc[nn][reg] + bv);
        }
    }
    __syncthreads();
    f16* ub = u + (long)b_local * 65536 + l0;
#pragma unroll
    for (int it = 0; it < 4; ++it) {
        int h = (tid >> 3) + 32 * it, seg = tid & 7;
        *(f16x8*)(ub + (long)h * 512 + seg * 8) = *(const f16x8*)&zs[h][seg * 8];
    }
}

// ---------------- conv (round-5 structure, L2-friendly grid order) --------------
// grid: x = l-tile (fastest), y = b-tile, z = h (slowest) -> tf/u L2 reuse
__global__ __launch_bounds__(256)
void conv_mfma(const f16* __restrict__ u, const f16* __restrict__ tf,
               const float* __restrict__ Dv, f16* __restrict__ y, int SC)
{
    __shared__ f16 As[64][72];
    __shared__ f16 ys[64][72];
    int Lt = blockIdx.x, b0 = blockIdx.y * 64, h = blockIdx.z;
    int l0 = Lt * 64;
    int tid = threadIdx.x, wave = tid >> 6, lane = tid & 63;

    f32x4 acc[4] = {};

    int ar = tid >> 2, aseg = tid & 3;
    bool arow_ok = (b0 + ar) < SC;
    const f16* ubase = u + ((long)(b0 + ar) * 128 + h) * 512;

    for (int jt = 0; jt <= Lt; ++jt) {
        f16x8 av0 = {}, av1 = {};
        if (arow_ok) {
            av0 = *(const f16x8*)(ubase + jt * 64 + aseg * 16);
            av1 = *(const f16x8*)(ubase + jt * 64 + aseg * 16 + 8);
        }
        __syncthreads();
        *(f16x8*)&As[ar][aseg * 16]     = av0;
        *(f16x8*)&As[ar][aseg * 16 + 8] = av1;
        __syncthreads();
        int d = Lt - jt;
        const f16* tfb = tf + (((long)h * 8 + d) * 8) * 512 + lane * 8;
#pragma unroll 2
        for (int s = 0; s < 2; ++s) {
            f16x8 af = *(const f16x8*)&As[16 * wave + (lane & 15)][32 * s + 8 * (lane >> 4)];
#pragma unroll
            for (int nn = 0; nn < 4; ++nn) {
                f16x8 bf = *(const f16x8*)(tfb + ((long)s * 4 + nn) * 512);
                acc[nn] = MFMA16(af, bf, acc[nn], 0, 0, 0);
            }
        }
    }
    float Dh = Dv[h];
#pragma unroll
    for (int nn = 0; nn < 4; ++nn) {
#pragma unroll
        for (int reg = 0; reg < 4; ++reg) {
            int bl = 16 * wave + 4 * (lane >> 4) + reg;
            int ll = 16 * nn + (lane & 15);
            ys[bl][ll] = (f16)gelu_f(acc[nn][reg] + (float)As[bl][ll] * Dh);
        }
    }
    __syncthreads();
#pragma unroll
    for (int it = 0; it < 2; ++it) {
        int unit = tid + 256 * it;
        int r = unit >> 3, seg = unit & 7;
        if (b0 + r < SC)
            *(f16x8*)(y + ((long)(b0 + r) * 128 + h) * 512 + l0 + seg * 8)
                = *(const f16x8*)&ys[r][seg * 8];
    }
}

// ---------------- glu v3: swizzled At/Ut stage + global B frags, 2 barriers -----
#define PITCH 144
__global__ __launch_bounds__(256)
void glu_mfma(const f16* __restrict__ y, const f16* __restrict__ u,
              const f16* __restrict__ Wfrag, const float* __restrict__ cb,
              const float* __restrict__ lng, const float* __restrict__ lnb,
              f16* __restrict__ xt)
{
    __shared__ f16 At[64][PITCH];
    __shared__ f16 Ut[64][PITCH];
    int b = blockIdx.x, l0 = blockIdx.y * 64;
    int tid = threadIdx.x, wave = tid >> 6, lane = tid & 63;

    // stage y^T / u^T, swizzled, h-paired f16x2 (2-way = free)
#pragma unroll
    for (int it = 0; it < 2; ++it) {
        int unit = tid + 256 * it;
        int hp = unit & 63, seg = unit >> 6;
        int h = hp * 2;
        const f16* yp = y + ((long)b * 128 + h) * 512 + l0 + seg * 8;
        const f16* up = u + ((long)b * 128 + h) * 512 + l0 + seg * 8;
        f16x8 ya = *(const f16x8*)yp;
        f16x8 yb = *(const f16x8*)(yp + 512);
        f16x8 ua = *(const f16x8*)up;
        f16x8 ub = *(const f16x8*)(up + 512);
#pragma unroll
        for (int q = 0; q < 8; ++q) {
            int l = seg * 8 + q;
            int ix = swz(h, l);
            f16x2 py; py[0] = ya[q]; py[1] = yb[q];
            f16x2 pu; pu[0] = ua[q]; pu[1] = ub[q];
            *(f16x2*)&At[l][ix] = py;
            *(f16x2*)&Ut[l][ix] = pu;
        }
    }
    __syncthreads();

    f32x4 acc[16] = {};
    const f16* bfp = Wfrag + lane * 8;
    int arow = 16 * wave + (lane & 15);
#pragma unroll
    for (int kk = 0; kk < 4; ++kk) {
        f16x8 af = *(const f16x8*)&At[arow][swz(kk * 32 + 8 * (lane >> 4), arow)];
#pragma unroll
        for (int nn = 0; nn < 16; ++nn) {
            f16x8 bf = *(const f16x8*)(bfp + (kk * 16 + nn) * 512);
            acc[nn] = MFMA16(af, bf, acc[nn], 0, 0, 0);
        }
    }

    // GLU + residual + LN stats
    float zz[8][4];
    float sum[4] = {0.f,0.f,0.f,0.f}, sq[4] = {0.f,0.f,0.f,0.f};
#pragma unroll
    for (int nn = 0; nn < 8; ++nn) {
        int o = nn * 16 + (lane & 15);
        float ca = cb[o], cbb = cb[o + 128];
#pragma unroll
        for (int reg = 0; reg < 4; ++reg) {
            int l = 16 * wave + 4 * (lane >> 4) + reg;
            float a = acc[nn][reg] + ca;
            float bbv = acc[nn + 8][reg] + cbb;
            float z = a * (1.0f / (1.0f + expf(-bbv))) + (float)Ut[l][swz(o, l)];
            zz[nn][reg] = z;
            sum[reg] += z; sq[reg] += z * z;
        }
    }
#pragma unroll
    for (int d = 1; d < 16; d <<= 1) {
#pragma unroll
        for (int reg = 0; reg < 4; ++reg) {
            sum[reg] += __shfl_xor(sum[reg], d);
            sq[reg]  += __shfl_xor(sq[reg], d);
        }
    }
    float mu[4], rs[4];
#pragma unroll
    for (int reg = 0; reg < 4; ++reg) {
        mu[reg] = sum[reg] * (1.0f / 128.0f);
        float var = sq[reg] * (1.0f / 128.0f) - mu[reg] * mu[reg];
        rs[reg] = rsqrtf(var + 1e-5f);
    }
    // write xt into At (each wave touches only its own rows -> no barrier needed)
#pragma unroll
    for (int nn = 0; nn < 8; ++nn) {
        int o = nn * 16 + (lane & 15);
        float g = lng[o], bta = lnb[o];
#pragma unroll
        for (int reg = 0; reg < 4; ++reg) {
            int l = 16 * wave + 4 * (lane >> 4) + reg;
            At[l][swz(o, l)] = (f16)((zz[nn][reg] - mu[reg]) * rs[reg] * g + bta);
        }
    }
    __syncthreads();
    // store token-major, unswizzling columns
    f16* xb = xt + ((long)b * 512 + l0) * 128;
#pragma unroll
    for (int it = 0; it < 4; ++it) {
        int unit = tid + 256 * it;
        int l = unit >> 4, seg = unit & 15;
        *(f16x8*)(xb + (long)l * 128 + seg * 8)
            = *(const f16x8*)&At[l][(seg ^ (l & 7)) * 8];
    }
}

// ---------------- d1 v3: direct-global A + global B frags + gelu + mean-pool ----
__global__ __launch_bounds__(256)
void d1_mfma(const f16* __restrict__ xt, const f16* __restrict__ Wfrag,
             const float* __restrict__ b1, float* __restrict__ hbar,
             long tok_base)
{
    __shared__ float red[4][16][16];
    int tid = threadIdx.x, wave = tid >> 6, lane = tid & 63;
    long m0 = (long)blockIdx.x * 64;

    const f16* arow = xt + (m0 + 16 * wave + (lane & 15)) * 128 + 8 * (lane >> 4);
    const f16* bfp = Wfrag + lane * 8;

    f32x4 acc[16] = {};
#pragma unroll
    for (int kk = 0; kk < 4; ++kk) {
        f16x8 af = *(const f16x8*)(arow + kk * 32);
#pragma unroll
        for (int nn = 0; nn < 16; ++nn) {
            f16x8 bf = *(const f16x8*)(bfp + (kk * 16 + nn) * 512);
            acc[nn] = MFMA16(af, bf, acc[nn], 0, 0, 0);
        }
    }
    long sent = (tok_base + m0) >> 9;
#pragma unroll
    for (int nn = 0; nn < 16; ++nn) {
        float bv = b1[nn * 16 + (lane & 15)];
        float s = 0.f;
#pragma unroll
        for (int reg = 0; reg < 4; ++reg)
            s += gelu_f(acc[nn][reg] + bv);
        s += __shfl_xor(s, 16);
        s += __shfl_xor(s, 32);
        if (lane < 16) red[wave][lane][nn] = s;
    }
    __syncthreads();
    if (wave == 0 && lane < 16) {
#pragma unroll
        for (int nn = 0; nn < 16; ++nn) {
            float tot = red[0][lane][nn] + red[1][lane][nn]
                      + red[2][lane][nn] + red[3][lane][nn];
            atomicAdd(&hbar[sent * 256 + nn * 16 + lane], tot * (1.0f / 512.0f));
        }
    }
}

// ======================= f32 kernels (sentence level + d2) ======================
__global__ __launch_bounds__(256)
void gemm_kernel(const float* __restrict__ A, const int* __restrict__ gather,
                 const float* __restrict__ W, const float* __restrict__ bias,
                 float* __restrict__ C, float* __restrict__ pool,
                 long m_base, int K, int N, int act, int poolLen)
{
    __shared__ float As[32][68];
    __shared__ float Ws[32][128];
    __shared__ float red[16][128];

    int tid = threadIdx.x;
    int tx = tid & 15, ty = tid >> 4;
    long m0 = (long)blockIdx.x * 64;
    int n0 = blockIdx.y * 128;

    int la_row = tid >> 2, la_k = (tid & 3) * 8;
    long arow = gather ? (long)gather[m_base + m0 + la_row] : (m0 + la_row);
    const float* Arow = A + arow * (long)K + la_k;
    int wk = tid >> 3, wn = (tid & 7) * 16;
    const float* Wp = W + (long)wk * N + n0 + wn;

    float acc[4][8];
#pragma unroll
    for (int i = 0; i < 4; ++i)
#pragma unroll
        for (int j = 0; j < 8; ++j) acc[i][j] = 0.f;

    for (int k0 = 0; k0 < K; k0 += 32) {
        float4 a0 = *(const float4*)(Arow + k0);
        float4 a1 = *(const float4*)(Arow + k0 + 4);
        const float* wp = Wp + (long)k0 * N;
        float4 w0 = *(const float4*)(wp);
        float4 w1 = *(const float4*)(wp + 4);
        float4 w2 = *(const float4*)(wp + 8);
        float4 w3 = *(const float4*)(wp + 12);
        __syncthreads();
        As[la_k + 0][la_row] = a0.x; As[la_k + 1][la_row] = a0.y;
        As[la_k + 2][la_row] = a0.z; As[la_k + 3][la_row] = a0.w;
        As[la_k + 4][la_row] = a1.x; As[la_k + 5][la_row] = a1.y;
        As[la_k + 6][la_row] = a1.z; As[la_k + 7][la_row] = a1.w;
        *(float4*)&Ws[wk][wn]      = w0;
        *(float4*)&Ws[wk][wn + 4]  = w1;
        *(float4*)&Ws[wk][wn + 8]  = w2;
        *(float4*)&Ws[wk][wn + 12] = w3;
        __syncthreads();
#pragma unroll
        for (int kk = 0; kk < 32; ++kk) {
            float4 av  = *(const float4*)&As[kk][ty * 4];
            float4 wv0 = *(const float4*)&Ws[kk][tx * 4];
            float4 wv1 = *(const float4*)&Ws[kk][64 + tx * 4];
            float a_[4] = {av.x, av.y, av.z, av.w};
            float w_[8] = {wv0.x, wv0.y, wv0.z, wv0.w, wv1.x, wv1.y, wv1.z, wv1.w};
#pragma unroll
            for (int i = 0; i < 4; ++i)
#pragma unroll
                for (int j = 0; j < 8; ++j)
                    acc[i][j] = fmaf(a_[i], w_[j], acc[i][j]);
        }
    }

    float bv[8];
#pragma unroll
    for (int j = 0; j < 8; ++j) {
        int col = (j < 4) ? (tx * 4 + j) : (64 + tx * 4 + (j - 4));
        bv[j] = bias[n0 + col];
    }
#pragma unroll
    for (int i = 0; i < 4; ++i)
#pragma unroll
        for (int j = 0; j < 8; ++j) {
            float v = acc[i][j] + bv[j];
            if (act == 1) v = gelu_f(v);
            acc[i][j] = v;
        }

    if (pool) {
        float pv[8];
#pragma unroll
        for (int j = 0; j < 8; ++j)
            pv[j] = acc[0][j] + acc[1][j] + acc[2][j] + acc[3][j];
        __syncthreads();
#pragma unroll
        for (int j = 0; j < 8; ++j) {
            int col = (j < 4) ? (tx * 4 + j) : (64 + tx * 4 + (j - 4));
            red[ty][col] = pv[j];
        }
        __syncthreads();
        if (ty == 0) {
            long sent = (m_base + m0) / poolLen;
            float inv = 1.0f / (float)poolLen;
#pragma unroll
            for (int j = 0; j < 8; ++j) {
                int col = (j < 4) ? (tx * 4 + j) : (64 + tx * 4 + (j - 4));
                float s = 0.f;
#pragma unroll
                for (int t = 0; t < 16; ++t) s += red[t][col];
                atomicAdd(&pool[sent * N + n0 + col], s * inv);
            }
        }
    } else if (C) {
#pragma unroll
        for (int i = 0; i < 4; ++i) {
            long m = m0 + ty * 4 + i;
            float* cp = C + m * (long)N + n0;
            float4 s0 = {acc[i][0], acc[i][1], acc[i][2], acc[i][3]};
            float4 s1 = {acc[i][4], acc[i][5], acc[i][6], acc[i][7]};
            *(float4*)(cp + tx * 4) = s0;
            *(float4*)(cp + 64 + tx * 4) = s1;
        }
    }
}

__global__ __launch_bounds__(256)
void transpose_kernel(const float* __restrict__ in, float* __restrict__ out,
                      int L, int H)
{
    __shared__ float t[32][33];
    int b = blockIdx.x, l0 = blockIdx.y * 32, h0 = blockIdx.z * 32;
    int tid = threadIdx.x;
    int c = tid & 31, r = tid >> 5;
    const float* ib = in + ((long)b * L + l0) * H + h0;
#pragma unroll
    for (int i = 0; i < 4; ++i)
        t[r + 8 * i][c] = ib[(long)(r + 8 * i) * H + c];
    __syncthreads();
    float* ob = out + ((long)b * H + h0) * L + l0;
#pragma unroll
    for (int i = 0; i < 4; ++i)
        ob[(long)(r + 8 * i) * L + c] = t[c][r + 8 * i];
}

__global__ __launch_bounds__(256)
void conv_kernel(const float* __restrict__ u, const float* __restrict__ kmat,
                 float* __restrict__ y, int NB, int L)
{
    __shared__ float Ut[64][68];
    __shared__ float kwin[128];
    int h = blockIdx.x;
    int b0 = blockIdx.y * 64, l0 = blockIdx.z * 64;
    int tid = threadIdx.x, tx = tid & 15, ty = tid >> 4;
    const float* kh = kmat + (long)h * L;

    float acc[4][4];
#pragma unroll
    for (int i = 0; i < 4; ++i)
#pragma unroll
        for (int j = 0; j < 4; ++j) acc[i][j] = 0.f;

    int ur = tid >> 2, uc = (tid & 3) * 16;

    for (int j0 = 0; j0 <= l0 + 63; j0 += 64) {
        float4 u0 = {0,0,0,0}, u1 = {0,0,0,0}, u2 = {0,0,0,0}, u3 = {0,0,0,0};
        if (b0 + ur < NB) {
            const float* up = u + ((long)(b0 + ur) * 128 + h) * L + j0 + uc;
            u0 = *(const float4*)up;        u1 = *(const float4*)(up + 4);
            u2 = *(const float4*)(up + 8);  u3 = *(const float4*)(up + 12);
        }
        float kv_ = 0.f;
        int d = l0 - j0 - 63 + tid;
        if (tid < 128) kv_ = (d >= 0 && d < L) ? kh[d] : 0.f;
        __syncthreads();
        {
            float uv[16] = {u0.x,u0.y,u0.z,u0.w, u1.x,u1.y,u1.z,u1.w,
                            u2.x,u2.y,u2.z,u2.w, u3.x,u3.y,u3.z,u3.w};
#pragma unroll
            for (int q = 0; q < 16; ++q) Ut[uc + q][ur] = uv[q];
        }
        if (tid < 128) kwin[tid] = kv_;
        __syncthreads();
#pragma unroll
        for (int jj = 0; jj < 64; ++jj) {
            float4 uv = *(const float4*)&Ut[jj][ty * 4];
            float ub[4] = {uv.x, uv.y, uv.z, uv.w};
            float kj[4];
#pragma unroll
            for (int j = 0; j < 4; ++j) kj[j] = kwin[63 + tx * 4 + j - jj];
#pragma unroll
            for (int i = 0; i < 4; ++i)
#pragma unroll
                for (int j = 0; j < 4; ++j)
                    acc[i][j] = fmaf(ub[i], kj[j], acc[i][j]);
        }
    }
#pragma unroll
    for (int i = 0; i < 4; ++i) {
        int b = b0 + ty * 4 + i;
        if (b < NB) {
            float4 s = {acc[i][0], acc[i][1], acc[i][2], acc[i][3]};
            *(float4*)(y + ((long)b * 128 + h) * L + l0 + tx * 4) = s;
        }
    }
}

__global__ __launch_bounds__(256)
void skipgelu_kernel(float* __restrict__ y, const float* __restrict__ u,
                     const float* __restrict__ D, int log2L, long total)
{
    long i = (long)blockIdx.x * 256 + threadIdx.x;
    long stride = (long)gridDim.x * 256;
    for (; i < total; i += stride) {
        int h = (int)((i >> log2L) & 127);
        float v = y[i] + u[i] * D[h];
        y[i] = gelu_f(v);
    }
}

__global__ __launch_bounds__(256)
void glu_kernel(const float* __restrict__ convW, const float* __restrict__ convb,
                const float* __restrict__ g, const float* u,
                float* z, int L)
{
    __shared__ float Wa[32][68], Wb[32][68], Gs[32][72];
    int b = blockIdx.x, o0 = blockIdx.y * 64, l0 = blockIdx.z * 64;
    int tid = threadIdx.x, tx = tid & 15, ty = tid >> 4;
    const float* gb = g + (long)b * 128 * L;

    float aa[4][4], ab[4][4];
#pragma unroll
    for (int i = 0; i < 4; ++i)
#pragma unroll
        for (int j = 0; j < 4; ++j) { aa[i][j] = 0.f; ab[i][j] = 0.f; }

    int wr = tid >> 2, wc = (tid & 3) * 8;
    int gh = tid >> 3, gl = (tid & 7) * 8;

    for (int k0 = 0; k0 < 128; k0 += 32) {
        float4 wa0 = *(const float4*)(convW + (long)(o0 + wr) * 128 + k0 + wc);
        float4 wa1 = *(const float4*)(convW + (long)(o0 + wr) * 128 + k0 + wc + 4);
        float4 wb0 = *(const float4*)(convW + (long)(o0 + wr + 128) * 128 + k0 + wc);
        float4 wb1 = *(const float4*)(convW + (long)(o0 + wr + 128) * 128 + k0 + wc + 4);
        float4 g0 = *(const float4*)(gb + (long)(k0 + gh) * L + l0 + gl);
        float4 g1 = *(const float4*)(gb + (long)(k0 + gh) * L + l0 + gl + 4);
        __syncthreads();
        {
            float wav[8] = {wa0.x,wa0.y,wa0.z,wa0.w, wa1.x,wa1.y,wa1.z,wa1.w};
            float wbv[8] = {wb0.x,wb0.y,wb0.z,wb0.w, wb1.x,wb1.y,wb1.z,wb1.w};
#pragma unroll
            for (int q = 0; q < 8; ++q) { Wa[wc + q][wr] = wav[q]; Wb[wc + q][wr] = wbv[q]; }
        }
        *(float4*)&Gs[gh][gl]     = g0;
        *(float4*)&Gs[gh][gl + 4] = g1;
        __syncthreads();
#pragma unroll
        for (int kk = 0; kk < 32; ++kk) {
            float4 wav = *(const float4*)&Wa[kk][ty * 4];
            float4 wbv = *(const float4*)&Wb[kk][ty * 4];
            float4 gv  = *(const float4*)&Gs[kk][tx * 4];
            float wa_[4] = {wav.x, wav.y, wav.z, wav.w};
            float wb_[4] = {wbv.x, wbv.y, wbv.z, wbv.w};
            float g_[4]  = {gv.x, gv.y, gv.z, gv.w};
#pragma unroll
            for (int i = 0; i < 4; ++i)
#pragma unroll
                for (int j = 0; j < 4; ++j) {
                    aa[i][j] = fmaf(wa_[i], g_[j], aa[i][j]);
                    ab[i][j] = fmaf(wb_[i], g_[j], ab[i][j]);
                }
        }
    }
#pragma unroll
    for (int i = 0; i < 4; ++i) {
        int o = o0 + ty * 4 + i;
        float ca = convb[o], cb2 = convb[o + 128];
        const float* up = u + ((long)b * 128 + o) * L + l0 + tx * 4;
        float4 uv = *(const float4*)up;
        float uu[4] = {uv.x, uv.y, uv.z, uv.w};
        float tmp[4];
#pragma unroll
        for (int j = 0; j < 4; ++j) {
            float av = aa[i][j] + ca;
            float bv2 = ab[i][j] + cb2;
            tmp[j] = av * (1.0f / (1.0f + expf(-bv2))) + uu[j];
        }
        float4 outv = {tmp[0], tmp[1], tmp[2], tmp[3]};
        *(float4*)(z + ((long)b * 128 + o) * L + l0 + tx * 4) = outv;
    }
}

__global__ __launch_bounds__(256)
void ln_kernel(const float* __restrict__ z, const float* __restrict__ gamma,
               const float* __restrict__ beta, float* __restrict__ out, int L)
{
    __shared__ float zs[128][65];
    __shared__ float mu_s[64], rs_s[64];
    int b = blockIdx.x, l0 = blockIdx.y * 64;
    const float* zb = z + (long)b * 128 * L;
    int tid = threadIdx.x;
    for (int idx = tid; idx < 128 * 64; idx += 256) {
        int h = idx >> 6, li = idx & 63;
        zs[h][li] = zb[(long)h * L + l0 + li];
    }
    __syncthreads();
    int l = tid >> 2, sub = tid & 3;
    float s = 0.f, sq = 0.f;
    for (int ii = 0; ii < 32; ++ii) {
        int i = (ii + sub * 8) & 31;
        float v = zs[sub * 32 + i][l];
        s += v; sq += v * v;
    }
    s += __shfl_xor(s, 1); sq += __shfl_xor(sq, 1);
    s += __shfl_xor(s, 2); sq += __shfl_xor(sq, 2);
    if (sub == 0) {
        float mu = s * (1.0f / 128.0f);
        float var = sq * (1.0f / 128.0f) - mu * mu;
        mu_s[l] = mu;
        rs_s[l] = rsqrtf(var + 1e-5f);
    }
    __syncthreads();
    for (int idx = tid; idx < 64 * 128; idx += 256) {
        int li = idx >> 7, h = idx & 127;
        float v = (zs[h][li] - mu_s[li]) * rs_s[li];
        out[((long)b * L + l0 + li) * 128 + h] = v * gamma[h] + beta[h];
    }
}

// =============================== host ========================================
extern "C" void kernel_launch(void* const* d_in, const int* in_sizes, int n_in,
                              void* d_out, int out_size, void* d_ws, size_t ws_size,
                              hipStream_t stream)
{
    const int* ids = (const int*)d_in[0];
    const float* emb = (const float*)d_in[1];
    const float* const* wp = (const float* const*)(d_in + 2);
    const float* const* sp = (const float* const*)(d_in + 18);
    enum {ENCW = 0, ENCB, LOGDT, CRE, CIM, LOGARE, AIM, DD,
          CONVW, CONVB, LNG, LNB, D1W, D1B, D2W, D2B};

    char* p = (char*)d_ws;
    auto alloc = [&](size_t bytes) {
        char* r = p; p += (bytes + 255) & ~(size_t)255; return r;
    };
    float* kW    = (float*)alloc(128 * 512 * 4);
    float* kS    = (float*)alloc(128 * 64 * 4);
    float* sents = (float*)alloc(512 * 256 * 4);
    float* hbar  = (float*)alloc(512 * 256 * 4);
    float* su    = (float*)alloc(512 * 128 * 4);
    float* subhl = (float*)alloc(512 * 128 * 4);
    float* sy    = (float*)alloc(512 * 128 * 4);
    float* szb   = (float*)alloc(512 * 128 * 4);
    float* sxt   = (float*)alloc(512 * 128 * 4);
    float* sh    = (float*)alloc(512 * 256 * 4);
    f16* encF    = (f16*)alloc(32768 * 2);
    f16* convF   = (f16*)alloc(32768 * 2);
    f16* d1F     = (f16*)alloc(32768 * 2);
    f16* tf      = (f16*)alloc(4194304L * 2);
    f16* emb16   = (f16*)alloc(12800000L * 2);

    long avail = (long)ws_size - (long)(p - (char*)d_ws);
    int SC = 512;
    while (SC > 1 && 3L * SC * 65536 * 2 + 1024 > avail) SC >>= 1;
    int nch = 512 / SC;
    f16* u_c  = (f16*)alloc((size_t)SC * 65536 * 2);
    f16* y_c  = (f16*)alloc((size_t)SC * 65536 * 2);
    f16* xt_c = (f16*)alloc((size_t)SC * 65536 * 2);

    // ---- precompute ----
    hipMemsetAsync(hbar, 0, 512 * 256 * 4, stream);
    packemb_kernel<<<6250, 256, 0, stream>>>(emb16, emb);
    s4k2_kernel<<<128, 256, 0, stream>>>(
        kW, wp[LOGDT], wp[CRE], wp[CIM], wp[LOGARE], wp[AIM], 512);
    s4k2_kernel<<<128, 256, 0, stream>>>(
        kS, sp[LOGDT], sp[CRE], sp[CIM], sp[LOGARE], sp[AIM], 64);
    packfrag_kernel<<<128, 256, 0, stream>>>(encF, wp[ENCW], 8, 128, 1);
    packfrag_kernel<<<128, 256, 0, stream>>>(convF, wp[CONVW], 16, 1, 128);
    packfrag_kernel<<<128, 256, 0, stream>>>(d1F, wp[D1W], 16, 256, 1);
    toep_kernel<<<16384, 256, 0, stream>>>(tf, kW);

    // ================= word level (f16 MFMA) =================
    for (int c = 0; c < nch; ++c) {
        long tok_base = (long)c * SC * 512;
        enc_mfma<<<SC * 8, 256, 0, stream>>>(
            emb16, ids, tok_base, encF, wp[ENCB], u_c);
        conv_mfma<<<dim3(8, (SC + 63) / 64, 128), 256, 0, stream>>>(
            u_c, tf, wp[DD], y_c, SC);
        glu_mfma<<<dim3(SC, 8), 256, 0, stream>>>(
            y_c, u_c, convF, wp[CONVB], wp[LNG], wp[LNB], xt_c);
        d1_mfma<<<SC * 8, 256, 0, stream>>>(
            xt_c, d1F, wp[D1B], hbar, tok_base);
    }
    // d2 on pooled h (pool-before-d2 exact: d2 linear)
    gemm_kernel<<<dim3(8, 2), 256, 0, stream>>>(
        hbar, nullptr, wp[D2W], wp[D2B], sents, nullptr, 0, 256, 256, 0, 0);

    // ================= sentence level (f32) =================
    gemm_kernel<<<dim3(8, 1), 256, 0, stream>>>(
        sents, nullptr, sp[ENCW], sp[ENCB], su, nullptr, 0, 256, 128, 0, 0);
    transpose_kernel<<<dim3(8, 2, 4), 256, 0, stream>>>(su, subhl, 64, 128);
    conv_kernel<<<dim3(128, 1, 1), 256, 0, stream>>>(subhl, kS, sy, 8, 64);
    skipgelu_kernel<<<256, 256, 0, stream>>>(sy, subhl, sp[DD], 6, 8L * 128 * 64);
    glu_kernel<<<dim3(8, 2, 1), 256, 0, stream>>>(
        sp[CONVW], sp[CONVB], sy, subhl, szb, 64);
    ln_kernel<<<dim3(8, 1), 256, 0, stream>>>(szb, sp[LNG], sp[LNB], sxt, 64);
    gemm_kernel<<<dim3(8, 2), 256, 0, stream>>>(
        sxt, nullptr, sp[D1W], sp[D1B], sh, nullptr, 0, 128, 256, 1, 0);
    gemm_kernel<<<dim3(8, 2), 256, 0, stream>>>(
        sh, nullptr, sp[D2W], sp[D2B], (float*)d_out, nullptr, 0, 256, 256, 0, 0);
}